// Round 15
// baseline (195.758 us; speedup 1.0000x reference)
//
#include <hip/hip_runtime.h>
#include <hip/hip_bf16.h>
#include <stdint.h>

#define S_LEN 2048
#define DIMSZ 2048
#define NH    16
#define HD    128
#define NQK   2176   // Q cols (2048) + K cols (128); V cols start here
#define NQKV  2304
#define NT2   (S_LEN / 128)

typedef short  bf16x8  __attribute__((ext_vector_type(8)));
typedef float  floatx4 __attribute__((ext_vector_type(4)));
typedef float  floatx16 __attribute__((ext_vector_type(16)));
typedef int    intx4   __attribute__((ext_vector_type(4)));
typedef unsigned short u16;

#define mfma32 __builtin_amdgcn_mfma_f32_32x32x16_bf16
#define LOG2E 1.4426950408889634f
#define C_SL2 (0.08838834764831845f * LOG2E)   // 1/sqrt(128) * log2(e)

// round-to-nearest-even f32 -> bf16 bits
__device__ __forceinline__ u16 f2bf(float x) {
  unsigned int u = __builtin_bit_cast(unsigned int, x);
  u = (u + 0x7FFFu + ((u >> 16) & 1u)) >> 16;
  return (u16)u;
}
__device__ __forceinline__ float bf2f(unsigned int bits) {
  return __builtin_bit_cast(float, bits << 16);
}

// v_cvt_pk_bf16_f32: word = (bf16(hi)<<16) | bf16(lo)   (plain VALU, no hazard)
__device__ __forceinline__ int cvtpk(float lo, float hi) {
  int r;
  asm("v_cvt_pk_bf16_f32 %0, %1, %2" : "=v"(r) : "v"(lo), "v"(hi));
  return r;
}

// 2^x — builtin so the compiler handles the TRANS wait-state hazard
#if __has_builtin(__builtin_amdgcn_exp2f)
__device__ __forceinline__ float fexp2(float x) { return __builtin_amdgcn_exp2f(x); }
#else
__device__ __forceinline__ float fexp2(float x) { return exp2f(x); }
#endif

// half swap via BUILTIN (hazard-modeled): a'[32:63]=b[0:31], b'[0:31]=a[32:63]
#if __has_builtin(__builtin_amdgcn_permlane32_swap)
__device__ __forceinline__ void half_swap(int& a, int& b) {
  auto r = __builtin_amdgcn_permlane32_swap(a, b, false, false);
  a = (int)r[0]; b = (int)r[1];
}
__device__ __forceinline__ float red_max32(float x) {
  int xi = __builtin_bit_cast(int, x);
  auto r = __builtin_amdgcn_permlane32_swap(xi, xi, false, false);
  return fmaxf(__builtin_bit_cast(float, (int)r[0]), __builtin_bit_cast(float, (int)r[1]));
}
__device__ __forceinline__ float red_add32(float x) {
  int xi = __builtin_bit_cast(int, x);
  auto r = __builtin_amdgcn_permlane32_swap(xi, xi, false, false);
  return __builtin_bit_cast(float, (int)r[0]) + __builtin_bit_cast(float, (int)r[1]);
}
#else
__device__ __forceinline__ void half_swap(int& a, int& b) {
  int as = __shfl_xor(a, 32);
  int bs = __shfl_xor(b, 32);
  int lane = threadIdx.x & 63;
  int na = (lane < 32) ? a : bs;
  int nb = (lane < 32) ? as : b;
  a = na; b = nb;
}
__device__ __forceinline__ float red_max32(float x) { return fmaxf(x, __shfl_xor(x, 32)); }
__device__ __forceinline__ float red_add32(float x) { return x + __shfl_xor(x, 32); }
#endif

// async global->LDS, 16 bytes per lane; LDS dest wave-uniform base (+lane*16 by HW)
__device__ __forceinline__ void gload16(const void* g, void* l) {
  __builtin_amdgcn_global_load_lds(
      reinterpret_cast<const __attribute__((address_space(1))) void*>(reinterpret_cast<uintptr_t>(g)),
      reinterpret_cast<__attribute__((address_space(3))) void*>(reinterpret_cast<uintptr_t>(l)),
      16, 0, 0);
}

// ---------------- merged prep: cvt + both transposes + bias concat ----------------
__global__ __launch_bounds__(256)
void k_prep(const float* __restrict__ hidden, u16* __restrict__ hb,
            const float* __restrict__ wq, const float* __restrict__ wk,
            const float* __restrict__ wv, u16* __restrict__ wqkvT,
            const float* __restrict__ wo, u16* __restrict__ woT,
            const float* __restrict__ bq, const float* __restrict__ bk,
            const float* __restrict__ bv, float* __restrict__ bqkv) {
  __shared__ float t[64][65];
  int bid = blockIdx.x;
  int tid = threadIdx.x;
  if (bid < 8192) {                      // hidden f32 -> bf16 (4 elems/thread)
    int i = bid * 256 + tid;
    float4 v = ((const float4*)hidden)[i];
    ushort4 o;
    o.x = f2bf(v.x); o.y = f2bf(v.y); o.z = f2bf(v.z); o.w = f2bf(v.w);
    ((ushort4*)hb)[i] = o;
    return;
  }
  bid -= 8192;
  const float* src;
  u16* dst;
  int N, scol0, orow0, r0;
  if (bid < 1152) {                      // wq|wk|wv transpose -> wqkvT
    orow0 = (bid % 36) * 64;
    r0 = (bid / 36) * 64;
    if (orow0 < 2048)      { src = wq; N = 2048; scol0 = orow0; }
    else if (orow0 < NQK)  { src = wk; N = 128;  scol0 = orow0 - 2048; }
    else                   { src = wv; N = 128;  scol0 = orow0 - NQK; }
    dst = wqkvT;
  } else if (bid < 1152 + 1024) {        // wo transpose -> woT
    int b2 = bid - 1152;
    orow0 = (b2 % 32) * 64;
    r0 = (b2 / 32) * 64;
    src = wo; N = 2048; scol0 = orow0;
    dst = woT;
  } else {                               // bias concat (9 blocks)
    int i = (bid - 1152 - 1024) * 256 + tid;
    if (i < NQKV) bqkv[i] = (i < 2048) ? bq[i] : (i < NQK ? bk[i - 2048] : bv[i - NQK]);
    return;
  }
  int lr = tid >> 6, lc = tid & 63;
#pragma unroll
  for (int i = 0; i < 16; ++i) {
    int r = lr + i * 4;
    t[r][lc] = src[(size_t)(r0 + r) * N + scol0 + lc];
  }
  __syncthreads();
#pragma unroll
  for (int i = 0; i < 16; ++i) {
    int r = lr + i * 4;
    dst[(size_t)(orow0 + r) * 2048 + r0 + lc] = f2bf(t[lc][r]);
  }
}

// ---------------- GEMM: C(MxN) = A(MxK) * Bt(NxK)^T + bias  (R8-proven) ----------
__device__ __forceinline__ void stage_tile(const u16* __restrict__ G, int ldg, int row0, int kt,
                                           u16* lbase, int wid, int lane) {
#pragma unroll
  for (int i = 0; i < 4; ++i) {
    int c   = (wid * 4 + i) * 64 + lane;
    int row = c >> 3, cin = c & 7;
    int cs  = cin ^ (row & 7);  // source pre-swizzle (rule #21)
    const u16* g = G + (size_t)(row0 + row) * ldg + kt * 64 + cs * 8;
    gload16(g, (char*)lbase + (wid * 4 + i) * 1024);
  }
}

template <int OMODE>
__global__ __launch_bounds__(256)
void k_gemm(const u16* __restrict__ A, const u16* __restrict__ Bt,
            const float* __restrict__ bias, void* __restrict__ Cout,
            u16* __restrict__ vt, int M, int N, int K) {
  __shared__ u16 lA[2][128 * 64];
  __shared__ u16 lB[2][128 * 64];
  const int tid = threadIdx.x, lane = tid & 63, wid = tid >> 6;
  const int wm = wid >> 1, wn = wid & 1;
  const int tm = blockIdx.x, tn = blockIdx.y;
  const int nk = K >> 6;

  stage_tile(A, K, tm * 128, 0, lA[0], wid, lane);
  stage_tile(Bt, K, tn * 128, 0, lB[0], wid, lane);
  __syncthreads();

  floatx4 acc[4][4] = {};
  int buf = 0;
  for (int kt = 0; kt < nk; ++kt) {
    if (kt + 1 < nk) {
      stage_tile(A, K, tm * 128, kt + 1, lA[buf ^ 1], wid, lane);
      stage_tile(Bt, K, tn * 128, kt + 1, lB[buf ^ 1], wid, lane);
    }
    const char* pa = (const char*)&lA[buf][0];
    const char* pb = (const char*)&lB[buf][0];
#pragma unroll
    for (int kk = 0; kk < 2; ++kk) {
      bf16x8 af[4], bfr[4];
      int gch = kk * 4 + (lane >> 4);
#pragma unroll
      for (int f = 0; f < 4; ++f) {
        int ra = wm * 64 + f * 16 + (lane & 15);
        af[f]  = *(const bf16x8*)(pa + ra * 128 + ((gch ^ (ra & 7)) << 4));
        int rb = wn * 64 + f * 16 + (lane & 15);
        bfr[f] = *(const bf16x8*)(pb + rb * 128 + ((gch ^ (rb & 7)) << 4));
      }
      __builtin_amdgcn_s_setprio(1);
#pragma unroll
      for (int fm = 0; fm < 4; ++fm)
#pragma unroll
        for (int fn = 0; fn < 4; ++fn)
          acc[fm][fn] = __builtin_amdgcn_mfma_f32_16x16x32_bf16(af[fm], bfr[fn], acc[fm][fn], 0, 0, 0);
      __builtin_amdgcn_s_setprio(0);
    }
    __syncthreads();
    buf ^= 1;
  }

#pragma unroll
  for (int fm = 0; fm < 4; ++fm)
#pragma unroll
    for (int fn = 0; fn < 4; ++fn)
#pragma unroll
      for (int r = 0; r < 4; ++r) {
        int rowg = tm * 128 + wm * 64 + fm * 16 + (lane >> 4) * 4 + r;
        int colg = tn * 128 + wn * 64 + fn * 16 + (lane & 15);
        float v = acc[fm][fn][r] + bias[colg];
        if constexpr (OMODE == 1) {
          ((float*)Cout)[(size_t)rowg * N + colg] = v;
        } else {
          if (colg < 2048) {
            ((u16*)Cout)[(size_t)rowg * N + colg] = f2bf(v * C_SL2);  // Q pre-scale
          } else if (colg < NQK) {
            ((u16*)Cout)[(size_t)rowg * N + colg] = f2bf(v);
          } else {  // V: store transposed vt[b][d][s]
            int d = colg - NQK;
            int bg = rowg >> 11, s = rowg & 2047;
            vt[((size_t)bg * HD + d) * S_LEN + s] = f2bf(v);
          }
        }
      }
}

// ---------------- flash attention: imm-offset refactor --------------------------
// grid (S/32, 2, B); 512 threads = 8 waves; wave w = head hg*8+w, same 32 q-rows.
// kt loop unrolled x2 (constexpr BUF) so every LDS read is lane-ptr + imm offset.
// K swizzle: chunk ^ (row&15) (unchanged). V/mask swizzle: (c&8)|((c^row)&7) so
// hf/dt/blk live in the immediate. Stage global addresses are incremental offsets.
__global__ __launch_bounds__(512)
void k_attn(const u16* __restrict__ qkv, const u16* __restrict__ vt,
            const float* __restrict__ mask, u16* __restrict__ attn) {
  __shared__ __align__(16) u16 lK[2][128 * 128];   // 64KB
  __shared__ __align__(16) u16 lV[2][128 * 128];   // 64KB
  __shared__ __align__(16) u16 lMb[2][32 * 128];   // 16KB
  const int tid = threadIdx.x, lane = tid & 63, wid = tid >> 6;
  const int qt = blockIdx.x, hg = blockIdx.y, b = blockIdx.z;
  const int h = hg * 8 + wid;
  const int q = lane & 31, h5 = lane >> 5;

  // hoist Q (B-frag: col=q); Q already scaled by C_SL2 in the QKV epilogue
  bf16x8 qf[8];
  const size_t qrow = (size_t)(b * S_LEN + qt * 32 + q);
#pragma unroll
  for (int cs = 0; cs < 8; ++cs)
    qf[cs] = *(const bf16x8*)(qkv + qrow * NQKV + h * HD + cs * 16 + h5 * 8);

  // hoisted per-lane LDS read pointers; all loop variation folds into imm offsets
  const char* aK[8];   // + BUF*32768 + blk*8192
  const char* aV[4];   // + BUF*32768 + dt*8192 + hf*128
  const char* aM[8];   // + BUF*8192  + hf*128
#pragma unroll
  for (int cs = 0; cs < 8; ++cs)
    aK[cs] = (const char*)lK + q * 256 + (((cs * 2 + h5) ^ (q & 15)) << 4);
#pragma unroll
  for (int ks = 0; ks < 4; ++ks)
    aV[ks] = (const char*)lV + q * 256 + (((ks * 2 + h5) ^ (q & 7)) << 4);
#pragma unroll
  for (int j = 0; j < 8; ++j)
    aM[j] = (const char*)lMb + q * 256 + ((j ^ (q & 7)) << 4) + h5 * 8;

  // incremental global stage offsets (bytes); advance by consts per kt
  int kOff[4], vOff[4];
#pragma unroll
  for (int i = 0; i < 4; ++i) {
    int r = (wid * 4 + i) * 4 + (lane >> 4);
    int cin = lane & 15;
    int csK = cin ^ (r & 15);
    kOff[i] = ((b * S_LEN + r) * NQKV + 2048 + csK * 8) * 2;
    int csV = (cin & 8) | ((cin ^ r) & 7);
    vOff[i] = ((b * HD + r) * S_LEN + csV * 8) * 2;
  }
  // mask write slot: logical chunk mc -> slot (mc&8)|((mc^mq)&7)
  const int mq = tid >> 4, mc = tid & 15;
  char* wM = (char*)lMb + mq * 256 + (((mc & 8) | ((mc ^ mq) & 7)) << 4);
  const float* mrow = mask + (size_t)b * S_LEN * S_LEN + (size_t)(qt * 32 + mq) * S_LEN + mc * 8;

  float m_ = -1e30f, l_ = 0.f;   // log2-domain running max / sum
  floatx16 acco[4] = {};         // O^T: col=q (lane-local), row = d

  // prologue: stage kt=0 into buf0
#pragma unroll
  for (int i = 0; i < 4; ++i) {
    gload16((const char*)qkv + kOff[i], (char*)lK + (wid * 4 + i) * 1024);
    gload16((const char*)vt + vOff[i], (char*)lV + (wid * 4 + i) * 1024);
    kOff[i] += 128 * NQKV * 2;
    vOff[i] += 128 * 2;
  }
  {
    floatx4 m0 = *(const floatx4*)(mrow);
    floatx4 m1 = *(const floatx4*)(mrow + 4);
    intx4 w;
    w[0] = cvtpk(m0[0] * LOG2E, m0[1] * LOG2E);
    w[1] = cvtpk(m0[2] * LOG2E, m0[3] * LOG2E);
    w[2] = cvtpk(m1[0] * LOG2E, m1[1] * LOG2E);
    w[3] = cvtpk(m1[2] * LOG2E, m1[3] * LOG2E);
    *(intx4*)wM = w;
    mrow += 128;
  }
  __syncthreads();

  for (int ktb = 0; ktb < NT2; ktb += 2) {
#pragma unroll
    for (int sub = 0; sub < 2; ++sub) {          // BUF = sub, constexpr after unroll
      const int BUF = sub;
      const int kt = ktb + sub;
      const bool pre = (kt + 1 < NT2);
      floatx4 mr0, mr1;
      if (pre) {
#pragma unroll
        for (int i = 0; i < 4; ++i) {
          gload16((const char*)qkv + kOff[i], (char*)lK + (BUF ^ 1) * 32768 + (wid * 4 + i) * 1024);
          gload16((const char*)vt + vOff[i], (char*)lV + (BUF ^ 1) * 32768 + (wid * 4 + i) * 1024);
          kOff[i] += 128 * NQKV * 2;
          vOff[i] += 128 * 2;
        }
        mr0 = *(const floatx4*)(mrow);
        mr1 = *(const floatx4*)(mrow + 4);
        mrow += 128;
      }

      // ---- C-init all four score accumulators from mask*log2e (imm-folded reads) ----
      floatx16 aA0, aA1, aB0, aB1;
#pragma unroll
      for (int rg = 0; rg < 4; ++rg) {
        ushort4 mu;
        mu = *(const ushort4*)(aM[rg] + BUF * 8192);
        aA0[rg * 4 + 0] = bf2f(mu.x); aA0[rg * 4 + 1] = bf2f(mu.y);
        aA0[rg * 4 + 2] = bf2f(mu.z); aA0[rg * 4 + 3] = bf2f(mu.w);
        mu = *(const ushort4*)(aM[4 + rg] + BUF * 8192);
        aA1[rg * 4 + 0] = bf2f(mu.x); aA1[rg * 4 + 1] = bf2f(mu.y);
        aA1[rg * 4 + 2] = bf2f(mu.z); aA1[rg * 4 + 3] = bf2f(mu.w);
        mu = *(const ushort4*)(aM[rg] + BUF * 8192 + 128);
        aB0[rg * 4 + 0] = bf2f(mu.x); aB0[rg * 4 + 1] = bf2f(mu.y);
        aB0[rg * 4 + 2] = bf2f(mu.z); aB0[rg * 4 + 3] = bf2f(mu.w);
        mu = *(const ushort4*)(aM[4 + rg] + BUF * 8192 + 128);
        aB1[rg * 4 + 0] = bf2f(mu.x); aB1[rg * 4 + 1] = bf2f(mu.y);
        aB1[rg * 4 + 2] = bf2f(mu.z); aB1[rg * 4 + 3] = bf2f(mu.w);
      }

      // ---- QK^T both halves: one 32-MFMA cluster (imm-folded K reads) ----
      __builtin_amdgcn_s_setprio(1);
#pragma unroll
      for (int cs = 0; cs < 8; ++cs) {
        bf16x8 k0 = *(const bf16x8*)(aK[cs] + BUF * 32768);
        bf16x8 k1 = *(const bf16x8*)(aK[cs] + BUF * 32768 + 8192);
        bf16x8 k2 = *(const bf16x8*)(aK[cs] + BUF * 32768 + 16384);
        bf16x8 k3 = *(const bf16x8*)(aK[cs] + BUF * 32768 + 24576);
        aA0 = mfma32(k0, qf[cs], aA0, 0, 0, 0);
        aA1 = mfma32(k1, qf[cs], aA1, 0, 0, 0);
        aB0 = mfma32(k2, qf[cs], aB0, 0, 0, 0);
        aB1 = mfma32(k3, qf[cs], aB1, 0, 0, 0);
      }
      __builtin_amdgcn_s_setprio(0);

      // ================= half 0: softmax + PV =================
      {
        float pm0 = -1e30f, pm1 = -1e30f, pm2 = -1e30f, pm3 = -1e30f;
#pragma unroll
        for (int r = 0; r < 16; r += 4) {
          pm0 = fmaxf(fmaxf(aA0[r + 0], aA0[r + 1]), pm0);
          pm1 = fmaxf(fmaxf(aA0[r + 2], aA0[r + 3]), pm1);
          pm2 = fmaxf(fmaxf(aA1[r + 0], aA1[r + 1]), pm2);
          pm3 = fmaxf(fmaxf(aA1[r + 2], aA1[r + 3]), pm3);
        }
        float rowm = red_max32(fmaxf(fmaxf(pm0, pm1), fmaxf(pm2, pm3)));
        if (__any(rowm > m_ + 11.5415603f)) {
          float mn = fmaxf(m_, rowm);
          float al = fexp2(m_ - mn);
          m_ = mn;
          l_ *= al;
#pragma unroll
          for (int dt = 0; dt < 4; ++dt) acco[dt] *= al;
        }
        float pr[32];
        float ps0 = 0.f, ps1 = 0.f, ps2 = 0.f, ps3 = 0.f;
#pragma unroll
        for (int i = 0; i < 16; i += 4) {
          float e0 = fexp2(aA0[i + 0] - m_); pr[i + 0] = e0; ps0 += e0;
          float e1 = fexp2(aA0[i + 1] - m_); pr[i + 1] = e1; ps1 += e1;
          float e2 = fexp2(aA0[i + 2] - m_); pr[i + 2] = e2; ps2 += e2;
          float e3 = fexp2(aA0[i + 3] - m_); pr[i + 3] = e3; ps3 += e3;
        }
#pragma unroll
        for (int i = 0; i < 16; i += 4) {
          float e0 = fexp2(aA1[i + 0] - m_); pr[16 + i + 0] = e0; ps0 += e0;
          float e1 = fexp2(aA1[i + 1] - m_); pr[16 + i + 1] = e1; ps1 += e1;
          float e2 = fexp2(aA1[i + 2] - m_); pr[16 + i + 2] = e2; ps2 += e2;
          float e3 = fexp2(aA1[i + 3] - m_); pr[16 + i + 3] = e3; ps3 += e3;
        }
        l_ += red_add32((ps0 + ps1) + (ps2 + ps3));

        bf16x8 pf[4];
#pragma unroll
        for (int kb = 0; kb < 2; ++kb)
#pragma unroll
          for (int s = 0; s < 2; ++s) {
            int base = kb * 16 + s * 8;
            int A0 = cvtpk(pr[base + 0], pr[base + 1]);
            int A1 = cvtpk(pr[base + 2], pr[base + 3]);
            int B0 = cvtpk(pr[base + 4], pr[base + 5]);
            int B1 = cvtpk(pr[base + 6], pr[base + 7]);
            half_swap(A0, B0);
            half_swap(A1, B1);
            intx4 w;
            w[0] = A0; w[1] = A1; w[2] = B0; w[3] = B1;
            pf[kb * 2 + s] = __builtin_bit_cast(bf16x8, w);
          }

        __builtin_amdgcn_s_setprio(1);
#pragma unroll
        for (int dt = 0; dt < 4; ++dt)
#pragma unroll
          for (int ks = 0; ks < 4; ++ks) {
            bf16x8 vf = *(const bf16x8*)(aV[ks] + BUF * 32768 + dt * 8192);
            acco[dt] = mfma32(vf, pf[ks], acco[dt], 0, 0, 0);
          }
        __builtin_amdgcn_s_setprio(0);
      }

      // ================= half 1: softmax + PV =================
      {
        float pm0 = -1e30f, pm1 = -1e30f, pm2 = -1e30f, pm3 = -1e30f;
#pragma unroll
        for (int r = 0; r < 16; r += 4) {
          pm0 = fmaxf(fmaxf(aB0[r + 0], aB0[r + 1]), pm0);
          pm1 = fmaxf(fmaxf(aB0[r + 2], aB0[r + 3]), pm1);
          pm2 = fmaxf(fmaxf(aB1[r + 0], aB1[r + 1]), pm2);
          pm3 = fmaxf(fmaxf(aB1[r + 2], aB1[r + 3]), pm3);
        }
        float rowm = red_max32(fmaxf(fmaxf(pm0, pm1), fmaxf(pm2, pm3)));
        if (__any(rowm > m_ + 11.5415603f)) {
          float mn = fmaxf(m_, rowm);
          float al = fexp2(m_ - mn);
          m_ = mn;
          l_ *= al;
#pragma unroll
          for (int dt = 0; dt < 4; ++dt) acco[dt] *= al;
        }
        float pr[32];
        float ps0 = 0.f, ps1 = 0.f, ps2 = 0.f, ps3 = 0.f;
#pragma unroll
        for (int i = 0; i < 16; i += 4) {
          float e0 = fexp2(aB0[i + 0] - m_); pr[i + 0] = e0; ps0 += e0;
          float e1 = fexp2(aB0[i + 1] - m_); pr[i + 1] = e1; ps1 += e1;
          float e2 = fexp2(aB0[i + 2] - m_); pr[i + 2] = e2; ps2 += e2;
          float e3 = fexp2(aB0[i + 3] - m_); pr[i + 3] = e3; ps3 += e3;
        }
#pragma unroll
        for (int i = 0; i < 16; i += 4) {
          float e0 = fexp2(aB1[i + 0] - m_); pr[16 + i + 0] = e0; ps0 += e0;
          float e1 = fexp2(aB1[i + 1] - m_); pr[16 + i + 1] = e1; ps1 += e1;
          float e2 = fexp2(aB1[i + 2] - m_); pr[16 + i + 2] = e2; ps2 += e2;
          float e3 = fexp2(aB1[i + 3] - m_); pr[16 + i + 3] = e3; ps3 += e3;
        }
        l_ += red_add32((ps0 + ps1) + (ps2 + ps3));

        bf16x8 pf[4];
#pragma unroll
        for (int kb = 0; kb < 2; ++kb)
#pragma unroll
          for (int s = 0; s < 2; ++s) {
            int base = kb * 16 + s * 8;
            int A0 = cvtpk(pr[base + 0], pr[base + 1]);
            int A1 = cvtpk(pr[base + 2], pr[base + 3]);
            int B0 = cvtpk(pr[base + 4], pr[base + 5]);
            int B1 = cvtpk(pr[base + 6], pr[base + 7]);
            half_swap(A0, B0);
            half_swap(A1, B1);
            intx4 w;
            w[0] = A0; w[1] = A1; w[2] = B0; w[3] = B1;
            pf[kb * 2 + s] = __builtin_bit_cast(bf16x8, w);
          }

        __builtin_amdgcn_s_setprio(1);
#pragma unroll
        for (int dt = 0; dt < 4; ++dt)
#pragma unroll
          for (int ks = 0; ks < 4; ++ks) {
            bf16x8 vf = *(const bf16x8*)(aV[ks] + BUF * 32768 + dt * 8192 + 128);
            acco[dt] = mfma32(vf, pf[ks], acco[dt], 0, 0, 0);
          }
        __builtin_amdgcn_s_setprio(0);
      }

      if (pre) {
        intx4 w;
        w[0] = cvtpk(mr0[0] * LOG2E, mr0[1] * LOG2E);
        w[1] = cvtpk(mr0[2] * LOG2E, mr0[3] * LOG2E);
        w[2] = cvtpk(mr1[0] * LOG2E, mr1[1] * LOG2E);
        w[3] = cvtpk(mr1[2] * LOG2E, mr1[3] * LOG2E);
        *(intx4*)(wM + (BUF ^ 1) * 8192) = w;
      }
      __syncthreads();
    }
  }

  // ---- epilogue: attn[q][h*HD + d] = O/l ----
  float inv = 1.0f / l_;
  u16* obase = attn + qrow * DIMSZ + h * HD;
#pragma unroll
  for (int dt = 0; dt < 4; ++dt)
#pragma unroll
    for (int rg = 0; rg < 4; ++rg) {
      int d0 = dt * 32 + rg * 8 + h5 * 4;
      ushort4 st;
      st.x = f2bf(acco[dt][rg * 4 + 0] * inv);
      st.y = f2bf(acco[dt][rg * 4 + 1] * inv);
      st.z = f2bf(acco[dt][rg * 4 + 2] * inv);
      st.w = f2bf(acco[dt][rg * 4 + 3] * inv);
      *(ushort4*)(obase + d0) = st;
    }
}

// ---------------- launch ----------------
extern "C" void kernel_launch(void* const* d_in, const int* in_sizes, int n_in,
                              void* d_out, int out_size, void* d_ws, size_t ws_size,
                              hipStream_t stream) {
  const float* hidden = (const float*)d_in[0];
  const float* mask   = (const float*)d_in[1];
  const float* wq = (const float*)d_in[2];
  const float* bq = (const float*)d_in[3];
  const float* wk = (const float*)d_in[4];
  const float* bk = (const float*)d_in[5];
  const float* wv = (const float*)d_in[6];
  const float* bv = (const float*)d_in[7];
  const float* wo = (const float*)d_in[8];
  const float* bo = (const float*)d_in[9];
  float* out = (float*)d_out;

  // workspace layout (total ~71.3 MB)
  char* ws = (char*)d_ws;
  u16*   hb    = (u16*)(ws);                    // hidden bf16: 4096x2048
  u16*   wqkvT = (u16*)(ws + 16777216);         // [wq^T; wk^T; wv^T]: 2304x2048
  u16*   woT   = (u16*)(ws + 26214400);         // wo^T: 2048x2048
  float* bqkv  = (float*)(ws + 34603008);       // 2304 f32
  u16*   qkv   = (u16*)(ws + 34612224);         // 4096x2304 (Q cols pre-scaled by C_SL2)
  u16*   vt    = (u16*)(ws + 53486592);         // 2 x 128 x 2048
  u16*   attn  = (u16*)(ws + 54535168);         // 4096x2048

  k_prep<<<dim3(10377), dim3(256), 0, stream>>>(hidden, hb, wq, wk, wv, wqkvT,
                                                wo, woT, bq, bk, bv, bqkv);
  k_gemm<0><<<dim3(32, 18), dim3(256), 0, stream>>>(hb, wqkvT, bqkv, (void*)qkv, vt, 4096, NQKV, 2048);
  k_attn<<<dim3(64, 2, 2), dim3(512), 0, stream>>>(qkv, vt, mask, attn);
  k_gemm<1><<<dim3(32, 16), dim3(256), 0, stream>>>(attn, woT, bo, (void*)out, (u16*)nullptr, 4096, 2048, 2048);
}

// Round 16
// 194.109 us; speedup vs baseline: 1.0085x; 1.0085x over previous
//
#include <hip/hip_runtime.h>
#include <hip/hip_bf16.h>
#include <stdint.h>

#define S_LEN 2048
#define DIMSZ 2048
#define NH    16
#define HD    128
#define NQK   2176   // Q cols (2048) + K cols (128); V cols start here
#define NQKV  2304
#define NT2   (S_LEN / 128)

typedef short  bf16x8  __attribute__((ext_vector_type(8)));
typedef float  floatx4 __attribute__((ext_vector_type(4)));
typedef float  floatx16 __attribute__((ext_vector_type(16)));
typedef int    intx4   __attribute__((ext_vector_type(4)));
typedef unsigned short u16;

#define mfma32 __builtin_amdgcn_mfma_f32_32x32x16_bf16
#define LOG2E 1.4426950408889634f
#define C_SL2 (0.08838834764831845f * LOG2E)   // 1/sqrt(128) * log2(e)

// round-to-nearest-even f32 -> bf16 bits
__device__ __forceinline__ u16 f2bf(float x) {
  unsigned int u = __builtin_bit_cast(unsigned int, x);
  u = (u + 0x7FFFu + ((u >> 16) & 1u)) >> 16;
  return (u16)u;
}
__device__ __forceinline__ float bf2f(unsigned int bits) {
  return __builtin_bit_cast(float, bits << 16);
}

// v_cvt_pk_bf16_f32: word = (bf16(hi)<<16) | bf16(lo)   (plain VALU, no hazard)
__device__ __forceinline__ int cvtpk(float lo, float hi) {
  int r;
  asm("v_cvt_pk_bf16_f32 %0, %1, %2" : "=v"(r) : "v"(lo), "v"(hi));
  return r;
}

// 2^x — builtin so the compiler handles the TRANS wait-state hazard
#if __has_builtin(__builtin_amdgcn_exp2f)
__device__ __forceinline__ float fexp2(float x) { return __builtin_amdgcn_exp2f(x); }
#else
__device__ __forceinline__ float fexp2(float x) { return exp2f(x); }
#endif

// half swap via BUILTIN (hazard-modeled): a'[32:63]=b[0:31], b'[0:31]=a[32:63]
#if __has_builtin(__builtin_amdgcn_permlane32_swap)
__device__ __forceinline__ void half_swap(int& a, int& b) {
  auto r = __builtin_amdgcn_permlane32_swap(a, b, false, false);
  a = (int)r[0]; b = (int)r[1];
}
__device__ __forceinline__ float red_max32(float x) {
  int xi = __builtin_bit_cast(int, x);
  auto r = __builtin_amdgcn_permlane32_swap(xi, xi, false, false);
  return fmaxf(__builtin_bit_cast(float, (int)r[0]), __builtin_bit_cast(float, (int)r[1]));
}
__device__ __forceinline__ float red_add32(float x) {
  int xi = __builtin_bit_cast(int, x);
  auto r = __builtin_amdgcn_permlane32_swap(xi, xi, false, false);
  return __builtin_bit_cast(float, (int)r[0]) + __builtin_bit_cast(float, (int)r[1]);
}
#else
__device__ __forceinline__ void half_swap(int& a, int& b) {
  int as = __shfl_xor(a, 32);
  int bs = __shfl_xor(b, 32);
  int lane = threadIdx.x & 63;
  int na = (lane < 32) ? a : bs;
  int nb = (lane < 32) ? as : b;
  a = na; b = nb;
}
__device__ __forceinline__ float red_max32(float x) { return fmaxf(x, __shfl_xor(x, 32)); }
__device__ __forceinline__ float red_add32(float x) { return x + __shfl_xor(x, 32); }
#endif

// async global->LDS, 16 bytes per lane; LDS dest wave-uniform base (+lane*16 by HW)
__device__ __forceinline__ void gload16(const void* g, void* l) {
  __builtin_amdgcn_global_load_lds(
      reinterpret_cast<const __attribute__((address_space(1))) void*>(reinterpret_cast<uintptr_t>(g)),
      reinterpret_cast<__attribute__((address_space(3))) void*>(reinterpret_cast<uintptr_t>(l)),
      16, 0, 0);
}

// ---------------- merged prep: cvt + both transposes + bias concat ----------------
__global__ __launch_bounds__(256)
void k_prep(const float* __restrict__ hidden, u16* __restrict__ hb,
            const float* __restrict__ wq, const float* __restrict__ wk,
            const float* __restrict__ wv, u16* __restrict__ wqkvT,
            const float* __restrict__ wo, u16* __restrict__ woT,
            const float* __restrict__ bq, const float* __restrict__ bk,
            const float* __restrict__ bv, float* __restrict__ bqkv) {
  __shared__ float t[64][65];
  int bid = blockIdx.x;
  int tid = threadIdx.x;
  if (bid < 8192) {                      // hidden f32 -> bf16 (4 elems/thread)
    int i = bid * 256 + tid;
    float4 v = ((const float4*)hidden)[i];
    ushort4 o;
    o.x = f2bf(v.x); o.y = f2bf(v.y); o.z = f2bf(v.z); o.w = f2bf(v.w);
    ((ushort4*)hb)[i] = o;
    return;
  }
  bid -= 8192;
  const float* src;
  u16* dst;
  int N, scol0, orow0, r0;
  if (bid < 1152) {                      // wq|wk|wv transpose -> wqkvT
    orow0 = (bid % 36) * 64;
    r0 = (bid / 36) * 64;
    if (orow0 < 2048)      { src = wq; N = 2048; scol0 = orow0; }
    else if (orow0 < NQK)  { src = wk; N = 128;  scol0 = orow0 - 2048; }
    else                   { src = wv; N = 128;  scol0 = orow0 - NQK; }
    dst = wqkvT;
  } else if (bid < 1152 + 1024) {        // wo transpose -> woT
    int b2 = bid - 1152;
    orow0 = (b2 % 32) * 64;
    r0 = (b2 / 32) * 64;
    src = wo; N = 2048; scol0 = orow0;
    dst = woT;
  } else {                               // bias concat (9 blocks)
    int i = (bid - 1152 - 1024) * 256 + tid;
    if (i < NQKV) bqkv[i] = (i < 2048) ? bq[i] : (i < NQK ? bk[i - 2048] : bv[i - NQK]);
    return;
  }
  int lr = tid >> 6, lc = tid & 63;
#pragma unroll
  for (int i = 0; i < 16; ++i) {
    int r = lr + i * 4;
    t[r][lc] = src[(size_t)(r0 + r) * N + scol0 + lc];
  }
  __syncthreads();
#pragma unroll
  for (int i = 0; i < 16; ++i) {
    int r = lr + i * 4;
    dst[(size_t)(orow0 + r) * 2048 + r0 + lc] = f2bf(t[lc][r]);
  }
}

// ---------------- GEMM: C(MxN) = A(MxK) * Bt(NxK)^T + bias  (R8-proven) ----------
__device__ __forceinline__ void stage_tile(const u16* __restrict__ G, int ldg, int row0, int kt,
                                           u16* lbase, int wid, int lane) {
#pragma unroll
  for (int i = 0; i < 4; ++i) {
    int c   = (wid * 4 + i) * 64 + lane;
    int row = c >> 3, cin = c & 7;
    int cs  = cin ^ (row & 7);  // source pre-swizzle (rule #21)
    const u16* g = G + (size_t)(row0 + row) * ldg + kt * 64 + cs * 8;
    gload16(g, (char*)lbase + (wid * 4 + i) * 1024);
  }
}

template <int OMODE>
__global__ __launch_bounds__(256)
void k_gemm(const u16* __restrict__ A, const u16* __restrict__ Bt,
            const float* __restrict__ bias, void* __restrict__ Cout,
            u16* __restrict__ vt, int M, int N, int K) {
  __shared__ u16 lA[2][128 * 64];
  __shared__ u16 lB[2][128 * 64];
  const int tid = threadIdx.x, lane = tid & 63, wid = tid >> 6;
  const int wm = wid >> 1, wn = wid & 1;
  const int tm = blockIdx.x, tn = blockIdx.y;
  const int nk = K >> 6;

  stage_tile(A, K, tm * 128, 0, lA[0], wid, lane);
  stage_tile(Bt, K, tn * 128, 0, lB[0], wid, lane);
  __syncthreads();

  floatx4 acc[4][4] = {};
  int buf = 0;
  for (int kt = 0; kt < nk; ++kt) {
    if (kt + 1 < nk) {
      stage_tile(A, K, tm * 128, kt + 1, lA[buf ^ 1], wid, lane);
      stage_tile(Bt, K, tn * 128, kt + 1, lB[buf ^ 1], wid, lane);
    }
    const char* pa = (const char*)&lA[buf][0];
    const char* pb = (const char*)&lB[buf][0];
#pragma unroll
    for (int kk = 0; kk < 2; ++kk) {
      bf16x8 af[4], bfr[4];
      int gch = kk * 4 + (lane >> 4);
#pragma unroll
      for (int f = 0; f < 4; ++f) {
        int ra = wm * 64 + f * 16 + (lane & 15);
        af[f]  = *(const bf16x8*)(pa + ra * 128 + ((gch ^ (ra & 7)) << 4));
        int rb = wn * 64 + f * 16 + (lane & 15);
        bfr[f] = *(const bf16x8*)(pb + rb * 128 + ((gch ^ (rb & 7)) << 4));
      }
      __builtin_amdgcn_s_setprio(1);
#pragma unroll
      for (int fm = 0; fm < 4; ++fm)
#pragma unroll
        for (int fn = 0; fn < 4; ++fn)
          acc[fm][fn] = __builtin_amdgcn_mfma_f32_16x16x32_bf16(af[fm], bfr[fn], acc[fm][fn], 0, 0, 0);
      __builtin_amdgcn_s_setprio(0);
    }
    __syncthreads();
    buf ^= 1;
  }

#pragma unroll
  for (int fm = 0; fm < 4; ++fm)
#pragma unroll
    for (int fn = 0; fn < 4; ++fn)
#pragma unroll
      for (int r = 0; r < 4; ++r) {
        int rowg = tm * 128 + wm * 64 + fm * 16 + (lane >> 4) * 4 + r;
        int colg = tn * 128 + wn * 64 + fn * 16 + (lane & 15);
        float v = acc[fm][fn][r] + bias[colg];
        if constexpr (OMODE == 1) {
          ((float*)Cout)[(size_t)rowg * N + colg] = v;
        } else {
          if (colg < 2048) {
            ((u16*)Cout)[(size_t)rowg * N + colg] = f2bf(v * C_SL2);  // Q pre-scale
          } else if (colg < NQK) {
            ((u16*)Cout)[(size_t)rowg * N + colg] = f2bf(v);
          } else {  // V: store transposed vt[b][d][s]
            int d = colg - NQK;
            int bg = rowg >> 11, s = rowg & 2047;
            vt[((size_t)bg * HD + d) * S_LEN + s] = f2bf(v);
          }
        }
      }
}

// ---------------- flash attention: imm-offset + R14 conflict-free swizzle ----------
// grid (S/32, 2, B); 512 threads = 8 waves; wave w = head hg*8+w, same 32 q-rows.
// kt loop unrolled x2 (constexpr BUF): buf*32768 / dt*8192 fold into ds_read imm.
// ALL tiles use the R14 swizzle chunk^(row&15) (2-way max bank aliasing); hf/dt
// variation handled by MORE hoisted pointers (aK[8], aV[8], aM[16]), not swizzle.
__global__ __launch_bounds__(512)
void k_attn(const u16* __restrict__ qkv, const u16* __restrict__ vt,
            const float* __restrict__ mask, u16* __restrict__ attn) {
  __shared__ __align__(16) u16 lK[2][128 * 128];   // 64KB
  __shared__ __align__(16) u16 lV[2][128 * 128];   // 64KB
  __shared__ __align__(16) u16 lMb[2][32 * 128];   // 16KB
  const int tid = threadIdx.x, lane = tid & 63, wid = tid >> 6;
  const int qt = blockIdx.x, hg = blockIdx.y, b = blockIdx.z;
  const int h = hg * 8 + wid;
  const int q = lane & 31, h5 = lane >> 5;

  // hoist Q (B-frag: col=q); Q already scaled by C_SL2 in the QKV epilogue
  bf16x8 qf[8];
  const size_t qrow = (size_t)(b * S_LEN + qt * 32 + q);
#pragma unroll
  for (int cs = 0; cs < 8; ++cs)
    qf[cs] = *(const bf16x8*)(qkv + qrow * NQKV + h * HD + cs * 16 + h5 * 8);

  // hoisted per-lane LDS read pointers (R14 swizzle ^(q&15) everywhere)
  const char* aK[8];   // + BUF*32768 + blk*8192
  const char* aV[8];   // j = hf*4+ks; + BUF*32768 + dt*8192
  const char* aM[16];  // c = hf*8+kb*4+rg; + BUF*8192
#pragma unroll
  for (int cs = 0; cs < 8; ++cs)
    aK[cs] = (const char*)lK + q * 256 + (((cs * 2 + h5) ^ (q & 15)) << 4);
#pragma unroll
  for (int j = 0; j < 8; ++j)
    aV[j] = (const char*)lV + q * 256 + ((((j >> 2) * 8 + (j & 3) * 2 + h5) ^ (q & 15)) << 4);
#pragma unroll
  for (int c = 0; c < 16; ++c)
    aM[c] = (const char*)lMb + q * 256 + ((c ^ (q & 15)) << 4) + h5 * 8;

  // incremental global stage offsets (bytes); advance by consts per kt
  int kOff[4], vOff[4];
#pragma unroll
  for (int i = 0; i < 4; ++i) {
    int r = (wid * 4 + i) * 4 + (lane >> 4);
    int cin = lane & 15;
    int cs = cin ^ (r & 15);
    kOff[i] = ((b * S_LEN + r) * NQKV + 2048 + cs * 8) * 2;
    vOff[i] = ((b * HD + r) * S_LEN + cs * 8) * 2;
  }
  // mask write slot (R14): logical chunk mc -> slot mc^(mq&15)
  const int mq = tid >> 4, mc = tid & 15;
  char* wM = (char*)lMb + mq * 256 + ((mc ^ (mq & 15)) << 4);
  const float* mrow = mask + (size_t)b * S_LEN * S_LEN + (size_t)(qt * 32 + mq) * S_LEN + mc * 8;

  float m_ = -1e30f, l_ = 0.f;   // log2-domain running max / sum
  floatx16 acco[4] = {};         // O^T: col=q (lane-local), row = d

  // prologue: stage kt=0 into buf0
#pragma unroll
  for (int i = 0; i < 4; ++i) {
    gload16((const char*)qkv + kOff[i], (char*)lK + (wid * 4 + i) * 1024);
    gload16((const char*)vt + vOff[i], (char*)lV + (wid * 4 + i) * 1024);
    kOff[i] += 128 * NQKV * 2;
    vOff[i] += 128 * 2;
  }
  {
    floatx4 m0 = *(const floatx4*)(mrow);
    floatx4 m1 = *(const floatx4*)(mrow + 4);
    intx4 w;
    w[0] = cvtpk(m0[0] * LOG2E, m0[1] * LOG2E);
    w[1] = cvtpk(m0[2] * LOG2E, m0[3] * LOG2E);
    w[2] = cvtpk(m1[0] * LOG2E, m1[1] * LOG2E);
    w[3] = cvtpk(m1[2] * LOG2E, m1[3] * LOG2E);
    *(intx4*)wM = w;
    mrow += 128;
  }
  __syncthreads();

  for (int ktb = 0; ktb < NT2; ktb += 2) {
#pragma unroll
    for (int sub = 0; sub < 2; ++sub) {          // BUF = sub, constexpr after unroll
      const int BUF = sub;
      const int kt = ktb + sub;
      const bool pre = (kt + 1 < NT2);
      floatx4 mr0, mr1;
      if (pre) {
#pragma unroll
        for (int i = 0; i < 4; ++i) {
          gload16((const char*)qkv + kOff[i], (char*)lK + (BUF ^ 1) * 32768 + (wid * 4 + i) * 1024);
          gload16((const char*)vt + vOff[i], (char*)lV + (BUF ^ 1) * 32768 + (wid * 4 + i) * 1024);
          kOff[i] += 128 * NQKV * 2;
          vOff[i] += 128 * 2;
        }
        mr0 = *(const floatx4*)(mrow);
        mr1 = *(const floatx4*)(mrow + 4);
        mrow += 128;
      }

      // ---- C-init all four score accumulators from mask*log2e (imm-folded reads) ----
      floatx16 aA0, aA1, aB0, aB1;
#pragma unroll
      for (int rg = 0; rg < 4; ++rg) {
        ushort4 mu;
        mu = *(const ushort4*)(aM[rg] + BUF * 8192);
        aA0[rg * 4 + 0] = bf2f(mu.x); aA0[rg * 4 + 1] = bf2f(mu.y);
        aA0[rg * 4 + 2] = bf2f(mu.z); aA0[rg * 4 + 3] = bf2f(mu.w);
        mu = *(const ushort4*)(aM[4 + rg] + BUF * 8192);
        aA1[rg * 4 + 0] = bf2f(mu.x); aA1[rg * 4 + 1] = bf2f(mu.y);
        aA1[rg * 4 + 2] = bf2f(mu.z); aA1[rg * 4 + 3] = bf2f(mu.w);
        mu = *(const ushort4*)(aM[8 + rg] + BUF * 8192);
        aB0[rg * 4 + 0] = bf2f(mu.x); aB0[rg * 4 + 1] = bf2f(mu.y);
        aB0[rg * 4 + 2] = bf2f(mu.z); aB0[rg * 4 + 3] = bf2f(mu.w);
        mu = *(const ushort4*)(aM[12 + rg] + BUF * 8192);
        aB1[rg * 4 + 0] = bf2f(mu.x); aB1[rg * 4 + 1] = bf2f(mu.y);
        aB1[rg * 4 + 2] = bf2f(mu.z); aB1[rg * 4 + 3] = bf2f(mu.w);
      }

      // ---- QK^T both halves: one 32-MFMA cluster (imm-folded K reads) ----
      __builtin_amdgcn_s_setprio(1);
#pragma unroll
      for (int cs = 0; cs < 8; ++cs) {
        bf16x8 k0 = *(const bf16x8*)(aK[cs] + BUF * 32768);
        bf16x8 k1 = *(const bf16x8*)(aK[cs] + BUF * 32768 + 8192);
        bf16x8 k2 = *(const bf16x8*)(aK[cs] + BUF * 32768 + 16384);
        bf16x8 k3 = *(const bf16x8*)(aK[cs] + BUF * 32768 + 24576);
        aA0 = mfma32(k0, qf[cs], aA0, 0, 0, 0);
        aA1 = mfma32(k1, qf[cs], aA1, 0, 0, 0);
        aB0 = mfma32(k2, qf[cs], aB0, 0, 0, 0);
        aB1 = mfma32(k3, qf[cs], aB1, 0, 0, 0);
      }
      __builtin_amdgcn_s_setprio(0);

      // ================= half 0: softmax + PV =================
      {
        float pm0 = -1e30f, pm1 = -1e30f, pm2 = -1e30f, pm3 = -1e30f;
#pragma unroll
        for (int r = 0; r < 16; r += 4) {
          pm0 = fmaxf(fmaxf(aA0[r + 0], aA0[r + 1]), pm0);
          pm1 = fmaxf(fmaxf(aA0[r + 2], aA0[r + 3]), pm1);
          pm2 = fmaxf(fmaxf(aA1[r + 0], aA1[r + 1]), pm2);
          pm3 = fmaxf(fmaxf(aA1[r + 2], aA1[r + 3]), pm3);
        }
        float rowm = red_max32(fmaxf(fmaxf(pm0, pm1), fmaxf(pm2, pm3)));
        if (__any(rowm > m_ + 11.5415603f)) {
          float mn = fmaxf(m_, rowm);
          float al = fexp2(m_ - mn);
          m_ = mn;
          l_ *= al;
#pragma unroll
          for (int dt = 0; dt < 4; ++dt) acco[dt] *= al;
        }
        float pr[32];
        float ps0 = 0.f, ps1 = 0.f, ps2 = 0.f, ps3 = 0.f;
#pragma unroll
        for (int i = 0; i < 16; i += 4) {
          float e0 = fexp2(aA0[i + 0] - m_); pr[i + 0] = e0; ps0 += e0;
          float e1 = fexp2(aA0[i + 1] - m_); pr[i + 1] = e1; ps1 += e1;
          float e2 = fexp2(aA0[i + 2] - m_); pr[i + 2] = e2; ps2 += e2;
          float e3 = fexp2(aA0[i + 3] - m_); pr[i + 3] = e3; ps3 += e3;
        }
#pragma unroll
        for (int i = 0; i < 16; i += 4) {
          float e0 = fexp2(aA1[i + 0] - m_); pr[16 + i + 0] = e0; ps0 += e0;
          float e1 = fexp2(aA1[i + 1] - m_); pr[16 + i + 1] = e1; ps1 += e1;
          float e2 = fexp2(aA1[i + 2] - m_); pr[16 + i + 2] = e2; ps2 += e2;
          float e3 = fexp2(aA1[i + 3] - m_); pr[16 + i + 3] = e3; ps3 += e3;
        }
        l_ += red_add32((ps0 + ps1) + (ps2 + ps3));

        bf16x8 pf[4];
#pragma unroll
        for (int kb = 0; kb < 2; ++kb)
#pragma unroll
          for (int s = 0; s < 2; ++s) {
            int base = kb * 16 + s * 8;
            int A0 = cvtpk(pr[base + 0], pr[base + 1]);
            int A1 = cvtpk(pr[base + 2], pr[base + 3]);
            int B0 = cvtpk(pr[base + 4], pr[base + 5]);
            int B1 = cvtpk(pr[base + 6], pr[base + 7]);
            half_swap(A0, B0);
            half_swap(A1, B1);
            intx4 w;
            w[0] = A0; w[1] = A1; w[2] = B0; w[3] = B1;
            pf[kb * 2 + s] = __builtin_bit_cast(bf16x8, w);
          }

        __builtin_amdgcn_s_setprio(1);
#pragma unroll
        for (int dt = 0; dt < 4; ++dt)
#pragma unroll
          for (int ks = 0; ks < 4; ++ks) {
            bf16x8 vf = *(const bf16x8*)(aV[ks] + BUF * 32768 + dt * 8192);
            acco[dt] = mfma32(vf, pf[ks], acco[dt], 0, 0, 0);
          }
        __builtin_amdgcn_s_setprio(0);
      }

      // ================= half 1: softmax + PV =================
      {
        float pm0 = -1e30f, pm1 = -1e30f, pm2 = -1e30f, pm3 = -1e30f;
#pragma unroll
        for (int r = 0; r < 16; r += 4) {
          pm0 = fmaxf(fmaxf(aB0[r + 0], aB0[r + 1]), pm0);
          pm1 = fmaxf(fmaxf(aB0[r + 2], aB0[r + 3]), pm1);
          pm2 = fmaxf(fmaxf(aB1[r + 0], aB1[r + 1]), pm2);
          pm3 = fmaxf(fmaxf(aB1[r + 2], aB1[r + 3]), pm3);
        }
        float rowm = red_max32(fmaxf(fmaxf(pm0, pm1), fmaxf(pm2, pm3)));
        if (__any(rowm > m_ + 11.5415603f)) {
          float mn = fmaxf(m_, rowm);
          float al = fexp2(m_ - mn);
          m_ = mn;
          l_ *= al;
#pragma unroll
          for (int dt = 0; dt < 4; ++dt) acco[dt] *= al;
        }
        float pr[32];
        float ps0 = 0.f, ps1 = 0.f, ps2 = 0.f, ps3 = 0.f;
#pragma unroll
        for (int i = 0; i < 16; i += 4) {
          float e0 = fexp2(aB0[i + 0] - m_); pr[i + 0] = e0; ps0 += e0;
          float e1 = fexp2(aB0[i + 1] - m_); pr[i + 1] = e1; ps1 += e1;
          float e2 = fexp2(aB0[i + 2] - m_); pr[i + 2] = e2; ps2 += e2;
          float e3 = fexp2(aB0[i + 3] - m_); pr[i + 3] = e3; ps3 += e3;
        }
#pragma unroll
        for (int i = 0; i < 16; i += 4) {
          float e0 = fexp2(aB1[i + 0] - m_); pr[16 + i + 0] = e0; ps0 += e0;
          float e1 = fexp2(aB1[i + 1] - m_); pr[16 + i + 1] = e1; ps1 += e1;
          float e2 = fexp2(aB1[i + 2] - m_); pr[16 + i + 2] = e2; ps2 += e2;
          float e3 = fexp2(aB1[i + 3] - m_); pr[16 + i + 3] = e3; ps3 += e3;
        }
        l_ += red_add32((ps0 + ps1) + (ps2 + ps3));

        bf16x8 pf[4];
#pragma unroll
        for (int kb = 0; kb < 2; ++kb)
#pragma unroll
          for (int s = 0; s < 2; ++s) {
            int base = kb * 16 + s * 8;
            int A0 = cvtpk(pr[base + 0], pr[base + 1]);
            int A1 = cvtpk(pr[base + 2], pr[base + 3]);
            int B0 = cvtpk(pr[base + 4], pr[base + 5]);
            int B1 = cvtpk(pr[base + 6], pr[base + 7]);
            half_swap(A0, B0);
            half_swap(A1, B1);
            intx4 w;
            w[0] = A0; w[1] = A1; w[2] = B0; w[3] = B1;
            pf[kb * 2 + s] = __builtin_bit_cast(bf16x8, w);
          }

        __builtin_amdgcn_s_setprio(1);
#pragma unroll
        for (int dt = 0; dt < 4; ++dt)
#pragma unroll
          for (int ks = 0; ks < 4; ++ks) {
            bf16x8 vf = *(const bf16x8*)(aV[4 + ks] + BUF * 32768 + dt * 8192);
            acco[dt] = mfma32(vf, pf[ks], acco[dt], 0, 0, 0);
          }
        __builtin_amdgcn_s_setprio(0);
      }

      if (pre) {
        intx4 w;
        w[0] = cvtpk(mr0[0] * LOG2E, mr0[1] * LOG2E);
        w[1] = cvtpk(mr0[2] * LOG2E, mr0[3] * LOG2E);
        w[2] = cvtpk(mr1[0] * LOG2E, mr1[1] * LOG2E);
        w[3] = cvtpk(mr1[2] * LOG2E, mr1[3] * LOG2E);
        *(intx4*)(wM + (BUF ^ 1) * 8192) = w;
      }
      __syncthreads();
    }
  }

  // ---- epilogue: attn[q][h*HD + d] = O/l ----
  float inv = 1.0f / l_;
  u16* obase = attn + qrow * DIMSZ + h * HD;
#pragma unroll
  for (int dt = 0; dt < 4; ++dt)
#pragma unroll
    for (int rg = 0; rg < 4; ++rg) {
      int d0 = dt * 32 + rg * 8 + h5 * 4;
      ushort4 st;
      st.x = f2bf(acco[dt][rg * 4 + 0] * inv);
      st.y = f2bf(acco[dt][rg * 4 + 1] * inv);
      st.z = f2bf(acco[dt][rg * 4 + 2] * inv);
      st.w = f2bf(acco[dt][rg * 4 + 3] * inv);
      *(ushort4*)(obase + d0) = st;
    }
}

// ---------------- launch ----------------
extern "C" void kernel_launch(void* const* d_in, const int* in_sizes, int n_in,
                              void* d_out, int out_size, void* d_ws, size_t ws_size,
                              hipStream_t stream) {
  const float* hidden = (const float*)d_in[0];
  const float* mask   = (const float*)d_in[1];
  const float* wq = (const float*)d_in[2];
  const float* bq = (const float*)d_in[3];
  const float* wk = (const float*)d_in[4];
  const float* bk = (const float*)d_in[5];
  const float* wv = (const float*)d_in[6];
  const float* bv = (const float*)d_in[7];
  const float* wo = (const float*)d_in[8];
  const float* bo = (const float*)d_in[9];
  float* out = (float*)d_out;

  // workspace layout (total ~71.3 MB)
  char* ws = (char*)d_ws;
  u16*   hb    = (u16*)(ws);                    // hidden bf16: 4096x2048
  u16*   wqkvT = (u16*)(ws + 16777216);         // [wq^T; wk^T; wv^T]: 2304x2048
  u16*   woT   = (u16*)(ws + 26214400);         // wo^T: 2048x2048
  float* bqkv  = (float*)(ws + 34603008);       // 2304 f32
  u16*   qkv   = (u16*)(ws + 34612224);         // 4096x2304 (Q cols pre-scaled by C_SL2)
  u16*   vt    = (u16*)(ws + 53486592);         // 2 x 128 x 2048
  u16*   attn  = (u16*)(ws + 54535168);         // 4096x2048

  k_prep<<<dim3(10377), dim3(256), 0, stream>>>(hidden, hb, wq, wk, wv, wqkvT,
                                                wo, woT, bq, bk, bv, bqkv);
  k_gemm<0><<<dim3(32, 18), dim3(256), 0, stream>>>(hb, wqkvT, bqkv, (void*)qkv, vt, 4096, NQKV, 2048);
  k_attn<<<dim3(64, 2, 2), dim3(512), 0, stream>>>(qkv, vt, mask, attn);
  k_gemm<1><<<dim3(32, 16), dim3(256), 0, stream>>>(attn, woT, bo, (void*)out, (u16*)nullptr, 4096, 2048, 2048);
}

// Round 17
// 192.893 us; speedup vs baseline: 1.0149x; 1.0063x over previous
//
#include <hip/hip_runtime.h>
#include <hip/hip_bf16.h>
#include <stdint.h>

#define S_LEN 2048
#define DIMSZ 2048
#define NH    16
#define HD    128
#define NQK   2176   // Q cols (2048) + K cols (128); V cols start here
#define NQKV  2304
#define NT2   (S_LEN / 128)

typedef short  bf16x8  __attribute__((ext_vector_type(8)));
typedef float  floatx4 __attribute__((ext_vector_type(4)));
typedef float  floatx16 __attribute__((ext_vector_type(16)));
typedef int    intx4   __attribute__((ext_vector_type(4)));
typedef unsigned short u16;

#define mfma32 __builtin_amdgcn_mfma_f32_32x32x16_bf16
#define LOG2E 1.4426950408889634f
#define C_SL2 (0.08838834764831845f * LOG2E)   // 1/sqrt(128) * log2(e)

// round-to-nearest-even f32 -> bf16 bits
__device__ __forceinline__ u16 f2bf(float x) {
  unsigned int u = __builtin_bit_cast(unsigned int, x);
  u = (u + 0x7FFFu + ((u >> 16) & 1u)) >> 16;
  return (u16)u;
}
__device__ __forceinline__ float bf2f(unsigned int bits) {
  return __builtin_bit_cast(float, bits << 16);
}

// v_cvt_pk_bf16_f32: word = (bf16(hi)<<16) | bf16(lo)   (plain VALU, no hazard)
__device__ __forceinline__ int cvtpk(float lo, float hi) {
  int r;
  asm("v_cvt_pk_bf16_f32 %0, %1, %2" : "=v"(r) : "v"(lo), "v"(hi));
  return r;
}

// 2^x — builtin so the compiler handles the TRANS wait-state hazard
#if __has_builtin(__builtin_amdgcn_exp2f)
__device__ __forceinline__ float fexp2(float x) { return __builtin_amdgcn_exp2f(x); }
#else
__device__ __forceinline__ float fexp2(float x) { return exp2f(x); }
#endif

// half swap via BUILTIN (hazard-modeled): a'[32:63]=b[0:31], b'[0:31]=a[32:63]
#if __has_builtin(__builtin_amdgcn_permlane32_swap)
__device__ __forceinline__ void half_swap(int& a, int& b) {
  auto r = __builtin_amdgcn_permlane32_swap(a, b, false, false);
  a = (int)r[0]; b = (int)r[1];
}
__device__ __forceinline__ float red_max32(float x) {
  int xi = __builtin_bit_cast(int, x);
  auto r = __builtin_amdgcn_permlane32_swap(xi, xi, false, false);
  return fmaxf(__builtin_bit_cast(float, (int)r[0]), __builtin_bit_cast(float, (int)r[1]));
}
__device__ __forceinline__ float red_add32(float x) {
  int xi = __builtin_bit_cast(int, x);
  auto r = __builtin_amdgcn_permlane32_swap(xi, xi, false, false);
  return __builtin_bit_cast(float, (int)r[0]) + __builtin_bit_cast(float, (int)r[1]);
}
#else
__device__ __forceinline__ void half_swap(int& a, int& b) {
  int as = __shfl_xor(a, 32);
  int bs = __shfl_xor(b, 32);
  int lane = threadIdx.x & 63;
  int na = (lane < 32) ? a : bs;
  int nb = (lane < 32) ? as : b;
  a = na; b = nb;
}
__device__ __forceinline__ float red_max32(float x) { return fmaxf(x, __shfl_xor(x, 32)); }
__device__ __forceinline__ float red_add32(float x) { return x + __shfl_xor(x, 32); }
#endif

// async global->LDS, 16 bytes per lane; LDS dest wave-uniform base (+lane*16 by HW)
__device__ __forceinline__ void gload16(const void* g, void* l) {
  __builtin_amdgcn_global_load_lds(
      reinterpret_cast<const __attribute__((address_space(1))) void*>(reinterpret_cast<uintptr_t>(g)),
      reinterpret_cast<__attribute__((address_space(3))) void*>(reinterpret_cast<uintptr_t>(l)),
      16, 0, 0);
}

// ---------------- merged prep: cvt + both transposes + bias concat ----------------
__global__ __launch_bounds__(256)
void k_prep(const float* __restrict__ hidden, u16* __restrict__ hb,
            const float* __restrict__ wq, const float* __restrict__ wk,
            const float* __restrict__ wv, u16* __restrict__ wqkvT,
            const float* __restrict__ wo, u16* __restrict__ woT,
            const float* __restrict__ bq, const float* __restrict__ bk,
            const float* __restrict__ bv, float* __restrict__ bqkv) {
  __shared__ float t[64][65];
  int bid = blockIdx.x;
  int tid = threadIdx.x;
  if (bid < 8192) {                      // hidden f32 -> bf16 (4 elems/thread)
    int i = bid * 256 + tid;
    float4 v = ((const float4*)hidden)[i];
    ushort4 o;
    o.x = f2bf(v.x); o.y = f2bf(v.y); o.z = f2bf(v.z); o.w = f2bf(v.w);
    ((ushort4*)hb)[i] = o;
    return;
  }
  bid -= 8192;
  const float* src;
  u16* dst;
  int N, scol0, orow0, r0;
  if (bid < 1152) {                      // wq|wk|wv transpose -> wqkvT
    orow0 = (bid % 36) * 64;
    r0 = (bid / 36) * 64;
    if (orow0 < 2048)      { src = wq; N = 2048; scol0 = orow0; }
    else if (orow0 < NQK)  { src = wk; N = 128;  scol0 = orow0 - 2048; }
    else                   { src = wv; N = 128;  scol0 = orow0 - NQK; }
    dst = wqkvT;
  } else if (bid < 1152 + 1024) {        // wo transpose -> woT
    int b2 = bid - 1152;
    orow0 = (b2 % 32) * 64;
    r0 = (b2 / 32) * 64;
    src = wo; N = 2048; scol0 = orow0;
    dst = woT;
  } else {                               // bias concat (9 blocks)
    int i = (bid - 1152 - 1024) * 256 + tid;
    if (i < NQKV) bqkv[i] = (i < 2048) ? bq[i] : (i < NQK ? bk[i - 2048] : bv[i - NQK]);
    return;
  }
  int lr = tid >> 6, lc = tid & 63;
#pragma unroll
  for (int i = 0; i < 16; ++i) {
    int r = lr + i * 4;
    t[r][lc] = src[(size_t)(r0 + r) * N + scol0 + lc];
  }
  __syncthreads();
#pragma unroll
  for (int i = 0; i < 16; ++i) {
    int r = lr + i * 4;
    dst[(size_t)(orow0 + r) * 2048 + r0 + lc] = f2bf(t[lc][r]);
  }
}

// ---------------- GEMM: C(MxN) = A(MxK) * Bt(NxK)^T + bias  (R8-proven) ----------
__device__ __forceinline__ void stage_tile(const u16* __restrict__ G, int ldg, int row0, int kt,
                                           u16* lbase, int wid, int lane) {
#pragma unroll
  for (int i = 0; i < 4; ++i) {
    int c   = (wid * 4 + i) * 64 + lane;
    int row = c >> 3, cin = c & 7;
    int cs  = cin ^ (row & 7);  // source pre-swizzle (rule #21)
    const u16* g = G + (size_t)(row0 + row) * ldg + kt * 64 + cs * 8;
    gload16(g, (char*)lbase + (wid * 4 + i) * 1024);
  }
}

template <int OMODE>
__global__ __launch_bounds__(256)
void k_gemm(const u16* __restrict__ A, const u16* __restrict__ Bt,
            const float* __restrict__ bias, void* __restrict__ Cout,
            u16* __restrict__ vt, int M, int N, int K) {
  __shared__ u16 lA[2][128 * 64];
  __shared__ u16 lB[2][128 * 64];
  const int tid = threadIdx.x, lane = tid & 63, wid = tid >> 6;
  const int wm = wid >> 1, wn = wid & 1;
  const int tm = blockIdx.x, tn = blockIdx.y;
  const int nk = K >> 6;

  stage_tile(A, K, tm * 128, 0, lA[0], wid, lane);
  stage_tile(Bt, K, tn * 128, 0, lB[0], wid, lane);
  __syncthreads();

  floatx4 acc[4][4] = {};
  int buf = 0;
  for (int kt = 0; kt < nk; ++kt) {
    if (kt + 1 < nk) {
      stage_tile(A, K, tm * 128, kt + 1, lA[buf ^ 1], wid, lane);
      stage_tile(Bt, K, tn * 128, kt + 1, lB[buf ^ 1], wid, lane);
    }
    const char* pa = (const char*)&lA[buf][0];
    const char* pb = (const char*)&lB[buf][0];
#pragma unroll
    for (int kk = 0; kk < 2; ++kk) {
      bf16x8 af[4], bfr[4];
      int gch = kk * 4 + (lane >> 4);
#pragma unroll
      for (int f = 0; f < 4; ++f) {
        int ra = wm * 64 + f * 16 + (lane & 15);
        af[f]  = *(const bf16x8*)(pa + ra * 128 + ((gch ^ (ra & 7)) << 4));
        int rb = wn * 64 + f * 16 + (lane & 15);
        bfr[f] = *(const bf16x8*)(pb + rb * 128 + ((gch ^ (rb & 7)) << 4));
      }
      __builtin_amdgcn_s_setprio(1);
#pragma unroll
      for (int fm = 0; fm < 4; ++fm)
#pragma unroll
        for (int fn = 0; fn < 4; ++fn)
          acc[fm][fn] = __builtin_amdgcn_mfma_f32_16x16x32_bf16(af[fm], bfr[fn], acc[fm][fn], 0, 0, 0);
      __builtin_amdgcn_s_setprio(0);
    }
    __syncthreads();
    buf ^= 1;
  }

#pragma unroll
  for (int fm = 0; fm < 4; ++fm)
#pragma unroll
    for (int fn = 0; fn < 4; ++fn)
#pragma unroll
      for (int r = 0; r < 4; ++r) {
        int rowg = tm * 128 + wm * 64 + fm * 16 + (lane >> 4) * 4 + r;
        int colg = tn * 128 + wn * 64 + fn * 16 + (lane & 15);
        float v = acc[fm][fn][r] + bias[colg];
        if constexpr (OMODE == 1) {
          ((float*)Cout)[(size_t)rowg * N + colg] = v;
        } else {
          if (colg < 2048) {
            ((u16*)Cout)[(size_t)rowg * N + colg] = f2bf(v * C_SL2);  // Q pre-scale
          } else if (colg < NQK) {
            ((u16*)Cout)[(size_t)rowg * N + colg] = f2bf(v);
          } else {  // V: store transposed vt[b][d][s]
            int d = colg - NQK;
            int bg = rowg >> 11, s = rowg & 2047;
            vt[((size_t)bg * HD + d) * S_LEN + s] = f2bf(v);
          }
        }
      }
}

// ---------------- flash attention (R14-proven: 8-wave, swapped-operand, KVBLK=128,
// mask C-init, wide QK phase, 16-deep swizzle) ------------------------------------
__device__ __forceinline__ void stage_kv128(const u16* __restrict__ qkv, const u16* __restrict__ vt,
                                            int b, int kt, u16* lK, u16* lV, int wid, int lane) {
#pragma unroll
  for (int i = 0; i < 4; ++i) {
    int seg = wid * 4 + i;             // 0..31, 1KB each
    int r = seg * 4 + (lane >> 4);     // row 0..127
    int cin = lane & 15;
    int cs = cin ^ (r & 15);           // source pre-swizzle (rule #21)
    const u16* gk = qkv + (size_t)(b * S_LEN + kt * 128 + r) * NQKV + 2048 + cs * 8;
    gload16(gk, (char*)lK + seg * 1024);
    const u16* gv = vt + ((size_t)b * HD + r) * S_LEN + kt * 128 + cs * 8;
    gload16(gv, (char*)lV + seg * 1024);
  }
}

// mask tile -> bf16 LDS pre-scaled by LOG2E; 32 rows x 256B, 16B chunks, 16-deep XOR
__device__ __forceinline__ void mask_write128(u16* lMb, int mq, int mc, floatx4 m0, floatx4 m1) {
  intx4 w;
  w[0] = cvtpk(m0[0] * LOG2E, m0[1] * LOG2E);
  w[1] = cvtpk(m0[2] * LOG2E, m0[3] * LOG2E);
  w[2] = cvtpk(m1[0] * LOG2E, m1[1] * LOG2E);
  w[3] = cvtpk(m1[2] * LOG2E, m1[3] * LOG2E);
  *(intx4*)((char*)lMb + mq * 256 + ((mc ^ (mq & 15)) << 4)) = w;
}

__global__ __launch_bounds__(512)
void k_attn(const u16* __restrict__ qkv, const u16* __restrict__ vt,
            const float* __restrict__ mask, u16* __restrict__ attn) {
  __shared__ __align__(16) u16 lK[2][128 * 128];   // 64KB
  __shared__ __align__(16) u16 lV[2][128 * 128];   // 64KB
  __shared__ __align__(16) u16 lMb[2][32 * 128];   // 16KB
  const int tid = threadIdx.x, lane = tid & 63, wid = tid >> 6;
  const int qt = blockIdx.x, hg = blockIdx.y, b = blockIdx.z;
  const int h = hg * 8 + wid;
  const int q = lane & 31, h5 = lane >> 5;

  // hoist Q (B-frag: col=q, d = cs*16 + h5*8 + idx); Q already scaled by C_SL2
  bf16x8 qf[8];
  const size_t qrow = (size_t)(b * S_LEN + qt * 32 + q);
#pragma unroll
  for (int cs = 0; cs < 8; ++cs)
    qf[cs] = *(const bf16x8*)(qkv + qrow * NQKV + h * HD + cs * 16 + h5 * 8);

  // hoisted LDS byte offsets (loop-invariant)
  const int qb = q * 256;
  int offK[8], offVc[8], offM[16];
#pragma unroll
  for (int cs = 0; cs < 8; ++cs)
    offK[cs] = qb + (((cs * 2 + h5) ^ (q & 15)) << 4);
#pragma unroll
  for (int hf = 0; hf < 2; ++hf)
#pragma unroll
    for (int ks = 0; ks < 4; ++ks)
      offVc[hf * 4 + ks] = (((hf * 8 + ks * 2 + h5) ^ (q & 15)) << 4);
#pragma unroll
  for (int c = 0; c < 16; ++c)
    offM[c] = qb + ((c ^ (q & 15)) << 4) + h5 * 8;

  float m_ = -1e30f, l_ = 0.f;   // log2-domain running max / sum
  floatx16 acco[4] = {};         // O^T: col=q (lane-local), row = d

  // mask stage helpers
  const int mq = tid >> 4, mc = tid & 15;
  const float* mrow = mask + (size_t)b * S_LEN * S_LEN + (size_t)(qt * 32 + mq) * S_LEN + mc * 8;

  // prologue: stage kt=0
  stage_kv128(qkv, vt, b, 0, lK[0], lV[0], wid, lane);
  {
    floatx4 m0 = *(const floatx4*)(mrow);
    floatx4 m1 = *(const floatx4*)(mrow + 4);
    mask_write128(&lMb[0][0], mq, mc, m0, m1);
  }
  __syncthreads();

  int buf = 0;
  for (int kt = 0; kt < NT2; ++kt) {
    floatx4 mr0, mr1;
    if (kt + 1 < NT2) {
      stage_kv128(qkv, vt, b, kt + 1, lK[buf ^ 1], lV[buf ^ 1], wid, lane);
      mr0 = *(const floatx4*)(mrow + (size_t)(kt + 1) * 128);
      mr1 = *(const floatx4*)(mrow + (size_t)(kt + 1) * 128 + 4);
    }
    const char* pKb = (const char*)&lK[buf][0];
    const char* pVb = (const char*)&lV[buf][0];
    const char* pMb = (const char*)&lMb[buf][0];

    // ---- C-init all four score accumulators from mask*log2e ----
    floatx16 aA0, aA1, aB0, aB1;
#pragma unroll
    for (int rg = 0; rg < 4; ++rg) {
      ushort4 mu;
      mu = *(const ushort4*)(pMb + offM[0 * 8 + 0 * 4 + rg]);
      aA0[rg * 4 + 0] = bf2f(mu.x); aA0[rg * 4 + 1] = bf2f(mu.y);
      aA0[rg * 4 + 2] = bf2f(mu.z); aA0[rg * 4 + 3] = bf2f(mu.w);
      mu = *(const ushort4*)(pMb + offM[0 * 8 + 1 * 4 + rg]);
      aA1[rg * 4 + 0] = bf2f(mu.x); aA1[rg * 4 + 1] = bf2f(mu.y);
      aA1[rg * 4 + 2] = bf2f(mu.z); aA1[rg * 4 + 3] = bf2f(mu.w);
      mu = *(const ushort4*)(pMb + offM[1 * 8 + 0 * 4 + rg]);
      aB0[rg * 4 + 0] = bf2f(mu.x); aB0[rg * 4 + 1] = bf2f(mu.y);
      aB0[rg * 4 + 2] = bf2f(mu.z); aB0[rg * 4 + 3] = bf2f(mu.w);
      mu = *(const ushort4*)(pMb + offM[1 * 8 + 1 * 4 + rg]);
      aB1[rg * 4 + 0] = bf2f(mu.x); aB1[rg * 4 + 1] = bf2f(mu.y);
      aB1[rg * 4 + 2] = bf2f(mu.z); aB1[rg * 4 + 3] = bf2f(mu.w);
    }

    // ---- QK^T both halves: one 32-MFMA cluster ----
    __builtin_amdgcn_s_setprio(1);
#pragma unroll
    for (int cs = 0; cs < 8; ++cs) {
      bf16x8 k0 = *(const bf16x8*)(pKb + offK[cs]);
      bf16x8 k1 = *(const bf16x8*)(pKb + 8192 + offK[cs]);
      bf16x8 k2 = *(const bf16x8*)(pKb + 16384 + offK[cs]);
      bf16x8 k3 = *(const bf16x8*)(pKb + 24576 + offK[cs]);
      aA0 = mfma32(k0, qf[cs], aA0, 0, 0, 0);
      aA1 = mfma32(k1, qf[cs], aA1, 0, 0, 0);
      aB0 = mfma32(k2, qf[cs], aB0, 0, 0, 0);
      aB1 = mfma32(k3, qf[cs], aB1, 0, 0, 0);
    }
    __builtin_amdgcn_s_setprio(0);

    // ================= half 0: softmax + PV =================
    {
      float pm0 = -1e30f, pm1 = -1e30f, pm2 = -1e30f, pm3 = -1e30f;
#pragma unroll
      for (int r = 0; r < 16; r += 4) {
        pm0 = fmaxf(fmaxf(aA0[r + 0], aA0[r + 1]), pm0);
        pm1 = fmaxf(fmaxf(aA0[r + 2], aA0[r + 3]), pm1);
        pm2 = fmaxf(fmaxf(aA1[r + 0], aA1[r + 1]), pm2);
        pm3 = fmaxf(fmaxf(aA1[r + 2], aA1[r + 3]), pm3);
      }
      float rowm = red_max32(fmaxf(fmaxf(pm0, pm1), fmaxf(pm2, pm3)));
      if (__any(rowm > m_ + 11.5415603f)) {
        float mn = fmaxf(m_, rowm);
        float al = fexp2(m_ - mn);
        m_ = mn;
        l_ *= al;
#pragma unroll
        for (int dt = 0; dt < 4; ++dt) acco[dt] *= al;
      }
      float pr[32];
      float ps0 = 0.f, ps1 = 0.f, ps2 = 0.f, ps3 = 0.f;
#pragma unroll
      for (int i = 0; i < 16; i += 4) {
        float e0 = fexp2(aA0[i + 0] - m_); pr[i + 0] = e0; ps0 += e0;
        float e1 = fexp2(aA0[i + 1] - m_); pr[i + 1] = e1; ps1 += e1;
        float e2 = fexp2(aA0[i + 2] - m_); pr[i + 2] = e2; ps2 += e2;
        float e3 = fexp2(aA0[i + 3] - m_); pr[i + 3] = e3; ps3 += e3;
      }
#pragma unroll
      for (int i = 0; i < 16; i += 4) {
        float e0 = fexp2(aA1[i + 0] - m_); pr[16 + i + 0] = e0; ps0 += e0;
        float e1 = fexp2(aA1[i + 1] - m_); pr[16 + i + 1] = e1; ps1 += e1;
        float e2 = fexp2(aA1[i + 2] - m_); pr[16 + i + 2] = e2; ps2 += e2;
        float e3 = fexp2(aA1[i + 3] - m_); pr[16 + i + 3] = e3; ps3 += e3;
      }
      l_ += red_add32((ps0 + ps1) + (ps2 + ps3));

      bf16x8 pf[4];
#pragma unroll
      for (int kb = 0; kb < 2; ++kb)
#pragma unroll
        for (int s = 0; s < 2; ++s) {
          int base = kb * 16 + s * 8;
          int A0 = cvtpk(pr[base + 0], pr[base + 1]);
          int A1 = cvtpk(pr[base + 2], pr[base + 3]);
          int B0 = cvtpk(pr[base + 4], pr[base + 5]);
          int B1 = cvtpk(pr[base + 6], pr[base + 7]);
          half_swap(A0, B0);
          half_swap(A1, B1);
          intx4 w;
          w[0] = A0; w[1] = A1; w[2] = B0; w[3] = B1;
          pf[kb * 2 + s] = __builtin_bit_cast(bf16x8, w);
        }

      __builtin_amdgcn_s_setprio(1);
#pragma unroll
      for (int dt = 0; dt < 4; ++dt)
#pragma unroll
        for (int ks = 0; ks < 4; ++ks) {
          bf16x8 vf = *(const bf16x8*)(pVb + dt * 8192 + qb + offVc[ks]);
          acco[dt] = mfma32(vf, pf[ks], acco[dt], 0, 0, 0);
        }
      __builtin_amdgcn_s_setprio(0);
    }

    // ================= half 1: softmax + PV =================
    {
      float pm0 = -1e30f, pm1 = -1e30f, pm2 = -1e30f, pm3 = -1e30f;
#pragma unroll
      for (int r = 0; r < 16; r += 4) {
        pm0 = fmaxf(fmaxf(aB0[r + 0], aB0[r + 1]), pm0);
        pm1 = fmaxf(fmaxf(aB0[r + 2], aB0[r + 3]), pm1);
        pm2 = fmaxf(fmaxf(aB1[r + 0], aB1[r + 1]), pm2);
        pm3 = fmaxf(fmaxf(aB1[r + 2], aB1[r + 3]), pm3);
      }
      float rowm = red_max32(fmaxf(fmaxf(pm0, pm1), fmaxf(pm2, pm3)));
      if (__any(rowm > m_ + 11.5415603f)) {
        float mn = fmaxf(m_, rowm);
        float al = fexp2(m_ - mn);
        m_ = mn;
        l_ *= al;
#pragma unroll
        for (int dt = 0; dt < 4; ++dt) acco[dt] *= al;
      }
      float pr[32];
      float ps0 = 0.f, ps1 = 0.f, ps2 = 0.f, ps3 = 0.f;
#pragma unroll
      for (int i = 0; i < 16; i += 4) {
        float e0 = fexp2(aB0[i + 0] - m_); pr[i + 0] = e0; ps0 += e0;
        float e1 = fexp2(aB0[i + 1] - m_); pr[i + 1] = e1; ps1 += e1;
        float e2 = fexp2(aB0[i + 2] - m_); pr[i + 2] = e2; ps2 += e2;
        float e3 = fexp2(aB0[i + 3] - m_); pr[i + 3] = e3; ps3 += e3;
      }
#pragma unroll
      for (int i = 0; i < 16; i += 4) {
        float e0 = fexp2(aB1[i + 0] - m_); pr[16 + i + 0] = e0; ps0 += e0;
        float e1 = fexp2(aB1[i + 1] - m_); pr[16 + i + 1] = e1; ps1 += e1;
        float e2 = fexp2(aB1[i + 2] - m_); pr[16 + i + 2] = e2; ps2 += e2;
        float e3 = fexp2(aB1[i + 3] - m_); pr[16 + i + 3] = e3; ps3 += e3;
      }
      l_ += red_add32((ps0 + ps1) + (ps2 + ps3));

      bf16x8 pf[4];
#pragma unroll
      for (int kb = 0; kb < 2; ++kb)
#pragma unroll
        for (int s = 0; s < 2; ++s) {
          int base = kb * 16 + s * 8;
          int A0 = cvtpk(pr[base + 0], pr[base + 1]);
          int A1 = cvtpk(pr[base + 2], pr[base + 3]);
          int B0 = cvtpk(pr[base + 4], pr[base + 5]);
          int B1 = cvtpk(pr[base + 6], pr[base + 7]);
          half_swap(A0, B0);
          half_swap(A1, B1);
          intx4 w;
          w[0] = A0; w[1] = A1; w[2] = B0; w[3] = B1;
          pf[kb * 2 + s] = __builtin_bit_cast(bf16x8, w);
        }

      __builtin_amdgcn_s_setprio(1);
#pragma unroll
      for (int dt = 0; dt < 4; ++dt)
#pragma unroll
        for (int ks = 0; ks < 4; ++ks) {
          bf16x8 vf = *(const bf16x8*)(pVb + dt * 8192 + qb + offVc[4 + ks]);
          acco[dt] = mfma32(vf, pf[ks], acco[dt], 0, 0, 0);
        }
      __builtin_amdgcn_s_setprio(0);
    }

    if (kt + 1 < NT2)
      mask_write128(&lMb[buf ^ 1][0], mq, mc, mr0, mr1);
    __syncthreads();
    buf ^= 1;
  }

  // ---- epilogue: attn[q][h*HD + d] = O/l ----
  float inv = 1.0f / l_;
  u16* obase = attn + qrow * DIMSZ + h * HD;
#pragma unroll
  for (int dt = 0; dt < 4; ++dt)
#pragma unroll
    for (int rg = 0; rg < 4; ++rg) {
      int d0 = dt * 32 + rg * 8 + h5 * 4;
      ushort4 st;
      st.x = f2bf(acco[dt][rg * 4 + 0] * inv);
      st.y = f2bf(acco[dt][rg * 4 + 1] * inv);
      st.z = f2bf(acco[dt][rg * 4 + 2] * inv);
      st.w = f2bf(acco[dt][rg * 4 + 3] * inv);
      *(ushort4*)(obase + d0) = st;
    }
}

// ---------------- launch ----------------
extern "C" void kernel_launch(void* const* d_in, const int* in_sizes, int n_in,
                              void* d_out, int out_size, void* d_ws, size_t ws_size,
                              hipStream_t stream) {
  const float* hidden = (const float*)d_in[0];
  const float* mask   = (const float*)d_in[1];
  const float* wq = (const float*)d_in[2];
  const float* bq = (const float*)d_in[3];
  const float* wk = (const float*)d_in[4];
  const float* bk = (const float*)d_in[5];
  const float* wv = (const float*)d_in[6];
  const float* bv = (const float*)d_in[7];
  const float* wo = (const float*)d_in[8];
  const float* bo = (const float*)d_in[9];
  float* out = (float*)d_out;

  // workspace layout (total ~71.3 MB)
  char* ws = (char*)d_ws;
  u16*   hb    = (u16*)(ws);                    // hidden bf16: 4096x2048
  u16*   wqkvT = (u16*)(ws + 16777216);         // [wq^T; wk^T; wv^T]: 2304x2048
  u16*   woT   = (u16*)(ws + 26214400);         // wo^T: 2048x2048
  float* bqkv  = (float*)(ws + 34603008);       // 2304 f32
  u16*   qkv   = (u16*)(ws + 34612224);         // 4096x2304 (Q cols pre-scaled by C_SL2)
  u16*   vt    = (u16*)(ws + 53486592);         // 2 x 128 x 2048
  u16*   attn  = (u16*)(ws + 54535168);         // 4096x2048

  k_prep<<<dim3(10377), dim3(256), 0, stream>>>(hidden, hb, wq, wk, wv, wqkvT,
                                                wo, woT, bq, bk, bv, bqkv);
  k_gemm<0><<<dim3(32, 18), dim3(256), 0, stream>>>(hb, wqkvT, bqkv, (void*)qkv, vt, 4096, NQKV, 2048);
  k_attn<<<dim3(64, 2, 2), dim3(512), 0, stream>>>(qkv, vt, mask, attn);
  k_gemm<1><<<dim3(32, 16), dim3(256), 0, stream>>>(attn, woT, bo, (void*)out, (u16*)nullptr, 4096, 2048, 2048);
}